// Round 1
// baseline (370.174 us; speedup 1.0000x reference)
//
#include <hip/hip_runtime.h>
#include <stdint.h>

// AdaptiveGCN: B=8, L=128, D=768.
// Algebra used:
//  - denom == 2.0 exactly (softmax rows sum to 1)  -> fold as *0.5
//  - mask  == all False -> write 1024 zeros
//  - (ax+out)@gw + 2gb == (a+I)@(out@gw) + 2gb
//  - concat-linear decomposes: hi = x@w1[:D], hj = x@w1[D:]

typedef __attribute__((ext_vector_type(8))) short short8;
typedef __attribute__((ext_vector_type(8))) unsigned short ushort8;
typedef __attribute__((ext_vector_type(4))) unsigned short ushort4v;
typedef __attribute__((ext_vector_type(4))) float floatx4;

__device__ __forceinline__ unsigned short f2bf(float f) {
    union { float f; unsigned int u; } v; v.f = f;
    unsigned int r = (v.u + 0x7FFFu + ((v.u >> 16) & 1u)) >> 16;
    return (unsigned short)r;
}
__device__ __forceinline__ float bf2f(unsigned short h) {
    union { unsigned int u; float f; } v; v.u = ((unsigned int)h) << 16;
    return v.f;
}
__device__ __forceinline__ floatx4 mfma16(short8 a, short8 b, floatx4 c) {
    return __builtin_amdgcn_mfma_f32_16x16x32_bf16(a, b, c, 0, 0, 0);
}
// async global->LDS, 16B per lane; LDS dest is wave-uniform base + lane*16
__device__ __forceinline__ void gload16(const void* g, void* lds) {
    __builtin_amdgcn_global_load_lds(
        (const __attribute__((address_space(1))) void*)g,
        (__attribute__((address_space(3))) void*)lds, 16, 0, 0);
}

// ---------------- prep: transpose fp32 -> bf16 [n][k] layouts ----------------
struct TJob { const float* src; unsigned short* dst; int R, C; };
struct TJobs { TJob j[6]; };

__global__ void trans_kernel(TJobs jobs) {
    const TJob jb = jobs.j[blockIdx.z];
    const int c0 = blockIdx.x * 32, r0 = blockIdx.y * 32;
    if (c0 >= jb.C || r0 >= jb.R) return;
    __shared__ float tile[32][33];
    const int x = threadIdx.x, y = threadIdx.y;  // 32 x 8
    #pragma unroll
    for (int yy = y; yy < 32; yy += 8)
        tile[yy][x] = jb.src[(r0 + yy) * jb.C + (c0 + x)];
    __syncthreads();
    #pragma unroll
    for (int yy = y; yy < 32; yy += 8)
        jb.dst[(c0 + yy) * jb.R + (r0 + x)] = f2bf(tile[x][yy]);
}

// x fp32 -> bf16 copy; also zero the mask region of d_out (mask is all-False)
__global__ void convx_kernel(const float* __restrict__ x,
                             unsigned short* __restrict__ xbf,
                             float* __restrict__ maskout) {
    int idx = blockIdx.x * 256 + threadIdx.x;  // grid exactly 786432/256
    xbf[idx] = f2bf(x[idx]);
    if (idx < 1024) maskout[idx] = 0.f;
}

// --------- 128x128-tile bf16 GEMM: C[m][n] = sum_k A[m][k]*Bm[n][k] ---------
// mode 0: hij epilogue (n<768 -> hi fp32; n>=768 -> hjb bf16). grid (12, 8)
// mode 1: Zt epilogue: zt[b][n][k_local] bf16 packed.           grid (6, 8)
__global__ __launch_bounds__(256) void gemm128_kernel(
    const unsigned short* __restrict__ A, const unsigned short* __restrict__ Bm,
    int mode, float* __restrict__ hi, unsigned short* __restrict__ hjb,
    unsigned short* __restrict__ zt) {
    __shared__ __align__(16) unsigned short sA[128 * 32];
    __shared__ __align__(16) unsigned short sB[128 * 32];
    const int n0 = blockIdx.x * 128, m0 = blockIdx.y * 128;
    const int t = threadIdx.x, wave = t >> 6, lane = t & 63;
    const int wm = wave >> 1, wn = wave & 1, col = lane & 15, q = lane >> 4;

    floatx4 acc[4][4];
    #pragma unroll
    for (int mt = 0; mt < 4; ++mt)
        #pragma unroll
        for (int nt = 0; nt < 4; ++nt) acc[mt][nt] = (floatx4){0.f, 0.f, 0.f, 0.f};

    for (int k0 = 0; k0 < 768; k0 += 32) {
        // XOR-swizzled chunk placement: chunk (row,half) lives at LDS chunk
        // row*4 + (half ^ ((row>>1)&3)); free since gptr is per-lane.
        #pragma unroll
        for (int c = 0; c < 2; ++c) {
            int cid = (wave * 2 + c) * 64 + lane;  // 0..511
            int rw = cid >> 2;
            int half = (cid & 3) ^ ((rw >> 1) & 3);
            gload16(A + (m0 + rw) * 768 + k0 + half * 8, (char*)sA + (wave * 2 + c) * 1024);
            gload16(Bm + (n0 + rw) * 768 + k0 + half * 8, (char*)sB + (wave * 2 + c) * 1024);
        }
        __syncthreads();
        short8 aF[4], bF[4];
        #pragma unroll
        for (int mt = 0; mt < 4; ++mt) {
            int r = wm * 64 + mt * 16 + col;
            aF[mt] = *(const short8*)&sA[r * 32 + (q ^ ((r >> 1) & 3)) * 8];
        }
        #pragma unroll
        for (int nt = 0; nt < 4; ++nt) {
            int r = wn * 64 + nt * 16 + col;
            bF[nt] = *(const short8*)&sB[r * 32 + (q ^ ((r >> 1) & 3)) * 8];
        }
        #pragma unroll
        for (int mt = 0; mt < 4; ++mt)
            #pragma unroll
            for (int nt = 0; nt < 4; ++nt)
                acc[mt][nt] = mfma16(aF[mt], bF[nt], acc[mt][nt]);
        __syncthreads();
    }
    // C layout: col = lane&15, row = q*4 + r (m89-verified)
    if (mode == 0) {
        #pragma unroll
        for (int mt = 0; mt < 4; ++mt)
            #pragma unroll
            for (int nt = 0; nt < 4; ++nt) {
                int mg = m0 + wm * 64 + mt * 16 + q * 4;
                int ng = n0 + wn * 64 + nt * 16 + col;
                if (ng < 768) {
                    #pragma unroll
                    for (int r = 0; r < 4; ++r) hi[(mg + r) * 768 + ng] = acc[mt][nt][r];
                } else {
                    #pragma unroll
                    for (int r = 0; r < 4; ++r) hjb[(mg + r) * 768 + (ng - 768)] = f2bf(acc[mt][nt][r]);
                }
            }
    } else {
        const int bb = blockIdx.y;  // 128 rows == one batch
        #pragma unroll
        for (int mt = 0; mt < 4; ++mt)
            #pragma unroll
            for (int nt = 0; nt < 4; ++nt) {
                int kl = wm * 64 + mt * 16 + q * 4;
                int ng = n0 + wn * 64 + nt * 16 + col;
                ushort4v pk;
                #pragma unroll
                for (int r = 0; r < 4; ++r) pk[r] = f2bf(acc[mt][nt][r]);
                *(ushort4v*)&zt[(bb * 768 + ng) * 128 + kl] = pk;  // 8B packed store
            }
    }
}

// ------------- edge kernel: one block per (b,i); full fused row -------------
// U = relu( relu(hi_i + hj + b1) @ w2 + b2 ); ew = sigmoid(U@w3 + b3);
// a_row = softmax(adj_row * ew + e_i)  -> abf (bf16)
__global__ __launch_bounds__(256) void edge_kernel(
    const float* __restrict__ hi, const unsigned short* __restrict__ hjb,
    const float* __restrict__ b1, const unsigned short* __restrict__ w2t,
    const float* __restrict__ b2, const float* __restrict__ w3,
    const float* __restrict__ b3, const float* __restrict__ adj,
    unsigned short* __restrict__ abf) {
    __shared__ __align__(16) float sHib[768];
    __shared__ __align__(16) unsigned short sH[128 * 40];  // stride 40: 2-way-only banks
    __shared__ __align__(16) unsigned short sW[128 * 32];  // unpadded (gload16) + swizzle
    __shared__ float sEw[128];
    __shared__ float sRed[4];

    const int t = threadIdx.x;
    const int row_i = blockIdx.x;  // b*128 + i
    const int b = row_i >> 7, i = row_i & 127;

    for (int k = t; k < 768; k += 256) sHib[k] = hi[row_i * 768 + k] + b1[k];
    if (t < 128) sEw[t] = 0.f;
    __syncthreads();

    const int wave = t >> 6, lane = t & 63;
    const int wm = wave >> 1, wn = wave & 1, col = lane & 15, q = lane >> 4;
    const int hj_j = t >> 1;
    const int hk = (t & 1) * 16;
    const unsigned short* hjrow = hjb + (b * 128 + hj_j) * 768;

    for (int nc = 0; nc < 3; ++nc) {
        floatx4 acc[4][4];
        #pragma unroll
        for (int mt = 0; mt < 4; ++mt)
            #pragma unroll
            for (int nt = 0; nt < 4; ++nt) acc[mt][nt] = (floatx4){0.f, 0.f, 0.f, 0.f};

        for (int k0 = 0; k0 < 768; k0 += 32) {
            #pragma unroll
            for (int c = 0; c < 2; ++c) {
                int cid = (wave * 2 + c) * 64 + lane;
                int rw = cid >> 2;
                int half = (cid & 3) ^ ((rw >> 1) & 3);
                gload16(w2t + (nc * 128 + rw) * 768 + k0 + half * 8,
                        (char*)sW + (wave * 2 + c) * 1024);
            }
            // form H tile: H[j][k] = relu(hi_i[k]+b1[k] + hj[j][k]); 16 elems/thread
            ushort8 h0 = *(const ushort8*)&hjrow[k0 + hk];
            ushort8 h1 = *(const ushort8*)&hjrow[k0 + hk + 8];
            ushort8 o0, o1;
            #pragma unroll
            for (int e = 0; e < 8; ++e) {
                float f0 = bf2f(h0[e]) + sHib[k0 + hk + e];
                float f1 = bf2f(h1[e]) + sHib[k0 + hk + 8 + e];
                o0[e] = f2bf(fmaxf(f0, 0.f));
                o1[e] = f2bf(fmaxf(f1, 0.f));
            }
            *(ushort8*)&sH[hj_j * 40 + hk] = o0;
            *(ushort8*)&sH[hj_j * 40 + hk + 8] = o1;
            __syncthreads();

            short8 aF[4], bF[4];
            #pragma unroll
            for (int mt = 0; mt < 4; ++mt) {
                int r = wm * 64 + mt * 16 + col;
                aF[mt] = *(const short8*)&sH[r * 40 + q * 8];
            }
            #pragma unroll
            for (int nt = 0; nt < 4; ++nt) {
                int r = wn * 64 + nt * 16 + col;
                bF[nt] = *(const short8*)&sW[r * 32 + (q ^ ((r >> 1) & 3)) * 8];
            }
            #pragma unroll
            for (int mt = 0; mt < 4; ++mt)
                #pragma unroll
                for (int nt = 0; nt < 4; ++nt)
                    acc[mt][nt] = mfma16(aF[mt], bF[nt], acc[mt][nt]);
            __syncthreads();
        }
        // epilogue: ew_partial[j] += sum_n relu(U+b2)*w3[n]
        #pragma unroll
        for (int mt = 0; mt < 4; ++mt) {
            float s0 = 0.f, s1 = 0.f, s2 = 0.f, s3 = 0.f;
            #pragma unroll
            for (int nt = 0; nt < 4; ++nt) {
                int n = nc * 128 + wn * 64 + nt * 16 + col;
                float w3n = w3[n], b2n = b2[n];
                s0 += fmaxf(acc[mt][nt][0] + b2n, 0.f) * w3n;
                s1 += fmaxf(acc[mt][nt][1] + b2n, 0.f) * w3n;
                s2 += fmaxf(acc[mt][nt][2] + b2n, 0.f) * w3n;
                s3 += fmaxf(acc[mt][nt][3] + b2n, 0.f) * w3n;
            }
            #pragma unroll
            for (int off = 1; off < 16; off <<= 1) {
                s0 += __shfl_xor(s0, off); s1 += __shfl_xor(s1, off);
                s2 += __shfl_xor(s2, off); s3 += __shfl_xor(s3, off);
            }
            if (col == 0) {
                int r = wm * 64 + mt * 16 + q * 4;
                atomicAdd(&sEw[r + 0], s0); atomicAdd(&sEw[r + 1], s1);
                atomicAdd(&sEw[r + 2], s2); atomicAdd(&sEw[r + 3], s3);
            }
        }
    }
    __syncthreads();
    // sigmoid -> adj*ew + I -> softmax over j (threads 0..127 hold j)
    float logit = -1e30f;
    if (t < 128) {
        float p = sEw[t] + b3[0];
        float ew = 1.f / (1.f + expf(-p));
        logit = adj[row_i * 128 + t] * ew + (t == i ? 1.f : 0.f);
    }
    float mx = logit;
    #pragma unroll
    for (int off = 1; off < 64; off <<= 1) mx = fmaxf(mx, __shfl_xor(mx, off));
    if (lane == 0 && wave < 2) sRed[wave] = mx;
    __syncthreads();
    mx = fmaxf(sRed[0], sRed[1]);
    float e = (t < 128) ? expf(logit - mx) : 0.f;
    float sm = e;
    #pragma unroll
    for (int off = 1; off < 64; off <<= 1) sm += __shfl_xor(sm, off);
    if (lane == 0 && wave < 2) sRed[2 + wave] = sm;
    __syncthreads();
    float tot = sRed[2] + sRed[3];
    if (t < 128) abf[row_i * 128 + t] = f2bf(e / tot);
}

// --- GCN second half: Y = (a+I)@Z, *0.5 + gb, relu, LayerNorm, -> out ---
// block: 16 rows x all 768 cols; wave w covers cols [w*192, w*192+192)
__global__ __launch_bounds__(256) void gy_kernel(
    const unsigned short* __restrict__ abf, const unsigned short* __restrict__ zt,
    const float* __restrict__ gb, const float* __restrict__ lng,
    const float* __restrict__ lnb, unsigned short* __restrict__ outbf,
    float* __restrict__ outf) {
    const int b = blockIdx.x >> 3;
    const int m0 = (blockIdx.x & 7) * 16;
    const int t = threadIdx.x, wave = t >> 6, lane = t & 63;
    const int col = lane & 15, q = lane >> 4;

    floatx4 acc[12];
    #pragma unroll
    for (int nt = 0; nt < 12; ++nt) acc[nt] = (floatx4){0.f, 0.f, 0.f, 0.f};

    const int mg = m0 + col;  // A-frag row (within batch)
    for (int k0 = 0; k0 < 128; k0 += 32) {
        short8 aF = *(const short8*)&abf[(b * 128 + mg) * 128 + k0 + q * 8];
        #pragma unroll
        for (int e = 0; e < 8; ++e) {  // += identity
            int k = k0 + q * 8 + e;
            if (k == mg) aF[e] = (short)f2bf(bf2f((unsigned short)aF[e]) + 1.f);
        }
        #pragma unroll
        for (int nt = 0; nt < 12; ++nt) {
            int n = wave * 192 + nt * 16 + col;
            short8 bF = *(const short8*)&zt[(b * 768 + n) * 128 + k0 + q * 8];
            acc[nt] = mfma16(aF, bF, acc[nt]);
        }
    }

    __shared__ float sSum[16], sSq[16];
    if (t < 16) { sSum[t] = 0.f; sSq[t] = 0.f; }
    __syncthreads();

    float ps[4] = {0.f, 0.f, 0.f, 0.f}, pq2[4] = {0.f, 0.f, 0.f, 0.f};
    #pragma unroll
    for (int nt = 0; nt < 12; ++nt) {
        int n = wave * 192 + nt * 16 + col;
        float g = gb[n];
        #pragma unroll
        for (int r = 0; r < 4; ++r) {
            float v = fmaxf(acc[nt][r] * 0.5f + g, 0.f);  // (.. + 2gb)/denom, denom==2
            acc[nt][r] = v;
            ps[r] += v; pq2[r] += v * v;
        }
    }
    #pragma unroll
    for (int off = 1; off < 16; off <<= 1) {
        #pragma unroll
        for (int r = 0; r < 4; ++r) {
            ps[r] += __shfl_xor(ps[r], off);
            pq2[r] += __shfl_xor(pq2[r], off);
        }
    }
    if (col == 0) {
        #pragma unroll
        for (int r = 0; r < 4; ++r) {
            atomicAdd(&sSum[q * 4 + r], ps[r]);
            atomicAdd(&sSq[q * 4 + r], pq2[r]);
        }
    }
    __syncthreads();
    float mean[4], rstd[4];
    #pragma unroll
    for (int r = 0; r < 4; ++r) {
        float mu = sSum[q * 4 + r] * (1.f / 768.f);
        float va = sSq[q * 4 + r] * (1.f / 768.f) - mu * mu;  // biased var (jnp.var)
        mean[r] = mu; rstd[r] = rsqrtf(va + 1e-5f);
    }
    #pragma unroll
    for (int nt = 0; nt < 12; ++nt) {
        int n = wave * 192 + nt * 16 + col;
        float ga = lng[n], be = lnb[n];
        #pragma unroll
        for (int r = 0; r < 4; ++r) {
            float o = (acc[nt][r] - mean[r]) * rstd[r] * ga + be;
            int rowg = b * 128 + m0 + q * 4 + r;
            if (outf) outf[rowg * 768 + n] = o;          // last layer -> d_out fp32
            else outbf[rowg * 768 + n] = f2bf(o);        // intermediate -> bf16
        }
    }
}

// ------------------------------- launch -------------------------------------
extern "C" void kernel_launch(void* const* d_in, const int* in_sizes, int n_in,
                              void* d_out, int out_size, void* d_ws, size_t ws_size,
                              hipStream_t stream) {
    const float* adj = (const float*)d_in[0];
    const float* x   = (const float*)d_in[1];
    const float* w1  = (const float*)d_in[2];
    const float* b1  = (const float*)d_in[3];
    const float* w2  = (const float*)d_in[4];
    const float* b2  = (const float*)d_in[5];
    const float* w3  = (const float*)d_in[6];
    const float* b3  = (const float*)d_in[7];
    const float* gw  = (const float*)d_in[8];
    const float* gb  = (const float*)d_in[9];
    const float* lng = (const float*)d_in[10];
    const float* lnb = (const float*)d_in[11];
    float* outp = (float*)d_out;  // 786432 out + 1024 mask

    char* ws = (char*)d_ws;
    unsigned short* w1t = (unsigned short*)(ws + 0);         // 1536x768 bf16 [n][k]
    unsigned short* w2t = (unsigned short*)(ws + 2359296);   // 384x768  bf16 [n][k]
    unsigned short* gwt = (unsigned short*)(ws + 2949120);   // 3x768x768 bf16 [n][k]
    unsigned short* xbf = (unsigned short*)(ws + 6488064);   // 1024x768 bf16
    float*          hi  = (float*)        (ws + 8060928);    // 1024x768 fp32
    unsigned short* hjb = (unsigned short*)(ws + 11206656);  // 1024x768 bf16
    unsigned short* abf = (unsigned short*)(ws + 12779520);  // 8x128x128 bf16
    unsigned short* zt  = (unsigned short*)(ws + 13041664);  // 8x768x128 bf16 (Z^T)
    unsigned short* obf = (unsigned short*)(ws + 14614528);  // 1024x768 bf16

    TJobs jobs;
    jobs.j[0] = { w1,              w1t,              768, 768 };
    jobs.j[1] = { w1 + 768 * 768,  w1t + 768 * 768,  768, 768 };
    jobs.j[2] = { w2,              w2t,              768, 384 };
    jobs.j[3] = { gw,              gwt,              768, 768 };
    jobs.j[4] = { gw + 589824,     gwt + 589824,     768, 768 };
    jobs.j[5] = { gw + 2 * 589824, gwt + 2 * 589824, 768, 768 };

    trans_kernel<<<dim3(24, 24, 6), dim3(32, 8), 0, stream>>>(jobs);
    convx_kernel<<<3072, 256, 0, stream>>>(x, xbf, outp + 786432);
    // hi | hjb = x @ [w1_top | w1_bot]
    gemm128_kernel<<<dim3(12, 8), 256, 0, stream>>>(xbf, w1t, 0, hi, hjb, nullptr);
    // fused edge MLP + softmax -> a (bf16)
    edge_kernel<<<1024, 256, 0, stream>>>(hi, hjb, b1, w2t, b2, w3, b3, adj, abf);
    // 3 GCN layers: Z^T = (out @ gw)^T ; out = LN(relu(((a+I)@Z)*0.5 + gb))
    for (int li = 0; li < 3; ++li) {
        const unsigned short* src = (li == 0) ? xbf : obf;
        gemm128_kernel<<<dim3(6, 8), 256, 0, stream>>>(src, gwt + li * 589824, 1,
                                                       nullptr, nullptr, zt);
        gy_kernel<<<64, 256, 0, stream>>>(abf, zt, gb + li * 768, lng + li * 768,
                                          lnb + li * 768, obf,
                                          (li == 2) ? outp : nullptr);
    }
}